// Round 24
// baseline (118.781 us; speedup 1.0000x reference)
//
#include <hip/hip_runtime.h>
#include <hip/hip_cooperative_groups.h>

#define TPB 1024
#define GRID 256   // coop capacity on this stack is <=256 blocks (r2/r7). Never exceed.

// r23 post-mortem: 117.7us (busy 57/stall 55); per-layer chain = detect,
// read, 1-wave fold, barrier, swizzle-heavy hi-finish, 1-wave 64-row sum,
// add+drain+gcnt. r24 micro-pack (conv code untouched):
// (1) fold split: w15->biasE, w14->biasO (row-stability proof unchanged;
//     both write identical gv -- benign).
// (2) publish split: waves 0-3 each sum 32 of 128 red rows, independent
//     atomicAdd -> drain -> gcnt+=1; consumer targets x4 (16L, final 112).
// (3) BFLY3 -> BFLY2 (masks 2,4; mask2 = DPP): red[128][64] (32KB),
//     writers (lane&7)<2, row=(wv<<3)|(lane>>3).

typedef float f2 __attribute__((ext_vector_type(2)));
static __device__ __forceinline__ f2 spl(float s) { f2 r; r.x = s; r.y = s; return r; }

__global__ void risnet_kernel(
    const float* __restrict__ channel,
    const float* __restrict__ We1, const float* __restrict__ be1,
    const float* __restrict__ We,  const float* __restrict__ be,
    const float* __restrict__ Wo1, const float* __restrict__ bo1,
    const float* __restrict__ Wo,  const float* __restrict__ bo,
    const float* __restrict__ W8,  const float* __restrict__ b8,
    float* __restrict__ out, float* __restrict__ part, int* __restrict__ gcnt)
{
  const int tid   = threadIdx.x;
  const int lane  = tid & 63;
  const int wv    = tid >> 6;                 // 0..15
  const int p     = tid & 1;                  // user-half: owns users 2p, 2p+1
  const int B     = blockIdx.x;
  const int b     = (B & 7) * 8 + ((B >> 3) & 7);  // same B%8 (XCD) per b-group (perf)
  const int chunk = B >> 6;                   // 0..3
  const int n     = (chunk << 9) | (tid >> 1);// 0..2047

  __shared__ __align__(16) float biasE[2][16][4];  // [L&1][h][u] parity dbuf
  __shared__ __align__(16) float biasO[2][16][4];
  __shared__ float red[128][64];                // [row=(wv<<3)|(lane>>3)][conv*32+j*4+u]
  __shared__ float gv[64];                      // per-b mean deltas (w14/w15 write same)
  __shared__ float fin;
  __shared__ int   lcnt;                        // cumulative per-wave publish count

  if (tid == 0) lcnt = 0;

  // per-thread channel slice, packed over the user pair: ch2[f] = {u=2p, u=2p+1}
  f2 ch2[4];
#pragma unroll
  for (int f = 0; f < 4; ++f) {
    ch2[f].x = channel[((b*4 + 2*p + 0)*4 + f)*2048 + n];
    ch2[f].y = channel[((b*4 + 2*p + 1)*4 + f)*2048 + n];
  }
  __syncthreads();   // lcnt init visible before any WAVE_DONE

  f2 el2[8], ol2[8];
  float cum0 = 0.f, cum1 = 0.f;   // w14/w15: cumulative part-row values per parity
  int   pubt = 16;                // publisher waves: lcnt target for next epoch

  // 2-level parity-preserving reduce: sums over the 4 same-parity lanes of
  // each 8-lane group (mask 2 lowers to DPP, mask 4 to one swizzle).
#define BFLY2(a0, a1) { \
  a0 += __shfl_xor(a0, 2, 64);  a1 += __shfl_xor(a1, 2, 64);  \
  a0 += __shfl_xor(a0, 4, 64);  a1 += __shfl_xor(a1, 4, 64); }

#define RED_W(base_col, a0, a1) \
  if ((lane & 7) < 2) { \
    red[(wv<<3)|(lane>>3)][(base_col) + 2*(lane&1) + 0] = a0; \
    red[(wv<<3)|(lane>>3)][(base_col) + 2*(lane&1) + 1] = a1; }

  // this wave's red[] rows for the current epoch are complete
#define WAVE_DONE() { \
  asm volatile("s_waitcnt lgkmcnt(0)" ::: "memory"); \
  if (lane == 0) \
    __hip_atomic_fetch_add(&lcnt, 1, __ATOMIC_RELAXED, __HIP_MEMORY_SCOPE_WORKGROUP); }

  // waves 0..3: poll LDS counter to epoch target, sum OWN 32 rows, atomicAdd
  // into the CUMULATIVE parity row, drain, bump group counter. No barrier.
#define PUBLISH_W03(par) \
  if (wv < 4) { \
    for (;;) { \
      int c = __hip_atomic_load(&lcnt, __ATOMIC_RELAXED, __HIP_MEMORY_SCOPE_WORKGROUP); \
      if (c >= pubt) break; \
      __builtin_amdgcn_s_sleep(0); \
    } \
    asm volatile("" ::: "memory"); \
    const int r0 = wv * 32; \
    float s0 = 0.f, s1 = 0.f, s2 = 0.f, s3 = 0.f; \
    _Pragma("unroll") for (int r = 0; r < 32; r += 4) { \
      s0 += red[r0+r+0][lane]; s1 += red[r0+r+1][lane]; \
      s2 += red[r0+r+2][lane]; s3 += red[r0+r+3][lane]; \
    } \
    unsafeAtomicAdd(&part[((par)*64 + b)*64 + lane], (s0+s1)+(s2+s3)); \
    asm volatile("s_waitcnt vmcnt(0)" ::: "memory"); \
    if (lane == 0) \
      __hip_atomic_fetch_add(&gcnt[b], 1, __ATOMIC_RELAXED, __HIP_MEMORY_SCOPE_AGENT); \
  } \
  pubt += 16;

  // single-address relaxed spin on the group counter
#define SPIN_CNT(tgt) { \
  for (;;) { \
    int c = __hip_atomic_load(&gcnt[b], __ATOMIC_RELAXED, __HIP_MEMORY_SCOPE_AGENT); \
    if (c >= (tgt)) break; \
    __builtin_amdgcn_s_sleep(1); \
  } \
  asm volatile("" ::: "memory"); }

  // packed 20-col dot product (ch 0..3, el 4..11, ol 20..27), BINIT = bias or 0
#define DOT20B(ACC, W0, W1, W2, W5, W6, BINIT) { \
  f2 v = (BINIT); \
  v = spl(W0.x)*ch2[0] + v; v = spl(W0.y)*ch2[1] + v; \
  v = spl(W0.z)*ch2[2] + v; v = spl(W0.w)*ch2[3] + v; \
  v = spl(W1.x)*el2[0] + v; v = spl(W1.y)*el2[1] + v; \
  v = spl(W1.z)*el2[2] + v; v = spl(W1.w)*el2[3] + v; \
  v = spl(W2.x)*el2[4] + v; v = spl(W2.y)*el2[5] + v; \
  v = spl(W2.z)*el2[6] + v; v = spl(W2.w)*el2[7] + v; \
  v = spl(W5.x)*ol2[0] + v; v = spl(W5.y)*ol2[1] + v; \
  v = spl(W5.z)*ol2[2] + v; v = spl(W5.w)*ol2[3] + v; \
  v = spl(W6.x)*ol2[4] + v; v = spl(W6.y)*ol2[5] + v; \
  v = spl(W6.z)*ol2[6] + v; v = spl(W6.w)*ol2[7] + v; \
  ACC = v; }

  // fold body: lane owns (u,h); folds ONE conv's bias from gv (in LDS)
#define FOLD_ONE(W, bvec, dst) { \
  const int u = lane & 3; \
  const int h = lane >> 2; \
  float bias = (bvec)[(L-1)*16 + h]; \
  _Pragma("unroll") for (int j = 0; j < 8; ++j) { \
    const float eg = gv[j*4 + u]; \
    const float so = gv[32+j*4+0] + gv[32+j*4+1] + gv[32+j*4+2] + gv[32+j*4+3]; \
    const float og = (so - gv[32 + j*4 + u]) * (1.f/3.f); \
    bias += (W)[h*36 + 12 + j] * eg + (W)[h*36 + 28 + j] * og; \
  } \
  (dst)[h][u] = bias; }

  // ---------------- layer 0 (Cin = 4, feats = ch) ----------------
  {
    f2 opl2[8];
#pragma unroll
    for (int h = 0; h < 16; ++h) {
      const float4 w = *(const float4*)(We1 + h*4);
      f2 a = spl(be1[h]);
      a = spl(w.x)*ch2[0] + a; a = spl(w.y)*ch2[1] + a;
      a = spl(w.z)*ch2[2] + a; a = spl(w.w)*ch2[3] + a;
      a.x = fmaxf(a.x, 0.f); a.y = fmaxf(a.y, 0.f);
      if (h < 8) el2[h] = a;
      else { float a0 = a.x, a1 = a.y; BFLY2(a0, a1); RED_W((h-8)*4, a0, a1); }
    }
#pragma unroll
    for (int h = 0; h < 16; ++h) {
      const float4 w = *(const float4*)(Wo1 + h*4);
      f2 a = spl(bo1[h]);
      a = spl(w.x)*ch2[0] + a; a = spl(w.y)*ch2[1] + a;
      a = spl(w.z)*ch2[2] + a; a = spl(w.w)*ch2[3] + a;
      a.x = fmaxf(a.x, 0.f); a.y = fmaxf(a.y, 0.f);
      if (h < 8) opl2[h] = a;
      else { float a0 = a.x, a1 = a.y; BFLY2(a0, a1); RED_W(32 + (h-8)*4, a0, a1); }
    }
    WAVE_DONE()
    PUBLISH_W03(0)
#pragma unroll
    for (int j = 0; j < 8; ++j) {
      const float s2 = opl2[j].x + opl2[j].y;
      const float s4 = s2 + __shfl_xor(s2, 1, 64);
      ol2[j] = (spl(s4) - opl2[j]) * spl(1.f/3.f);
    }
  }

  // ---------------- layers 1..6 (Cin = 36) ----------------
  for (int L = 1; L < 7; ++L) {
    const float* __restrict__ wEl = We + (L-1)*576;   // wave-uniform -> s_loads
    const float* __restrict__ wOl = Wo + (L-1)*576;
    const int pr = (L-1) & 1;      // parity row holding stats(L-1) cumulative
    const int pw = L & 1;          // parity row this layer publishes into
    const int bb = L & 1;          // bias parity buffer

    // --- phase 1: HI accumulators for BOTH convs, no bias (32 VGPR) ---
    f2 accHiE[8], accHiO[8];
#pragma unroll
    for (int h = 8; h < 16; ++h) {
      const float4* wr = (const float4*)(wEl + h*36);
      const float4 w0 = wr[0], w1 = wr[1], w2 = wr[2], w5 = wr[5], w6 = wr[6];
      DOT20B(accHiE[h-8], w0, w1, w2, w5, w6, spl(0.f))
    }
#pragma unroll
    for (int h = 8; h < 16; ++h) {
      const float4* wr = (const float4*)(wOl + h*36);
      const float4 w0 = wr[0], w1 = wr[1], w2 = wr[2], w5 = wr[5], w6 = wr[6];
      DOT20B(accHiO[h-8], w0, w1, w2, w5, w6, spl(0.f))
    }

    // --- w15/w14: spin, read ONE cumulative row, delta, fold E / fold O ---
    if (wv >= 14) {
      SPIN_CNT(16*L)
      float R = __hip_atomic_load(&part[(pr*64 + b)*64 + lane],
                                  __ATOMIC_RELAXED, __HIP_MEMORY_SCOPE_AGENT);
      float prev = pr ? cum1 : cum0;
      float d = R - prev;
      if (pr) cum1 = R; else cum0 = R;
      gv[lane] = d * (1.f/2048.f);   // w14 and w15 write identical values
      if (wv == 15) { FOLD_ONE(wEl, be, biasE[bb]) }
      else          { FOLD_ONE(wOl, bo, biasO[bb]) }
    }
    __syncthreads();   // the ONLY block barrier this layer: biases ready

    // --- hi finish: bias + relu + bfly only (NO conv on the publish path) ---
#pragma unroll
    for (int h = 8; h < 16; ++h) {
      f2 a = accHiE[h-8] + *(const f2*)&biasE[bb][h][2*p];
      float a0 = fmaxf(a.x, 0.f), a1 = fmaxf(a.y, 0.f);
      BFLY2(a0, a1); RED_W((h-8)*4, a0, a1);
    }
#pragma unroll
    for (int h = 8; h < 16; ++h) {
      f2 a = accHiO[h-8] + *(const f2*)&biasO[bb][h][2*p];
      float a0 = fmaxf(a.x, 0.f), a1 = fmaxf(a.y, 0.f);
      BFLY2(a0, a1); RED_W(32 + (h-8)*4, a0, a1);
    }
    WAVE_DONE()
    PUBLISH_W03(pw)   // waves 0-3 publish; others fall through to lo halves

    // --- lo convs in the publish shadow (bias-init, biases known) ---
    f2 eln2[8];
#pragma unroll
    for (int h = 0; h < 8; ++h) {
      const float4* wr = (const float4*)(wEl + h*36);
      const float4 w0 = wr[0], w1 = wr[1], w2 = wr[2], w5 = wr[5], w6 = wr[6];
      f2 a;
      DOT20B(a, w0, w1, w2, w5, w6, *(const f2*)&biasE[bb][h][2*p])
      a.x = fmaxf(a.x, 0.f); a.y = fmaxf(a.y, 0.f);
      eln2[h] = a;
    }
    f2 opl2[8];
#pragma unroll
    for (int h = 0; h < 8; ++h) {
      const float4* wr = (const float4*)(wOl + h*36);
      const float4 w0 = wr[0], w1 = wr[1], w2 = wr[2], w5 = wr[5], w6 = wr[6];
      f2 a;
      DOT20B(a, w0, w1, w2, w5, w6, *(const f2*)&biasO[bb][h][2*p])
      a.x = fmaxf(a.x, 0.f); a.y = fmaxf(a.y, 0.f);
      opl2[h] = a;
    }
#pragma unroll
    for (int j = 0; j < 8; ++j) {
      const float s2 = opl2[j].x + opl2[j].y;
      const float s4 = s2 + __shfl_xor(s2, 1, 64);
      ol2[j] = (spl(s4) - opl2[j]) * spl(1.f/3.f);
      el2[j] = eln2[j];
    }
  }

  // ---------------- final 1x1 conv + mean over users ----------------
  if (wv == 15) {   // layer 6 published parity 0; 7 epochs x 16 bumps = 112
    SPIN_CNT(112)
    float R = __hip_atomic_load(&part[(0*64 + b)*64 + lane],
                                __ATOMIC_RELAXED, __HIP_MEMORY_SCOPE_AGENT);
    gv[lane] = (R - cum0) * (1.f/2048.f);
    if (lane == 0) {
      float sf = b8[0];
#pragma unroll
      for (int j = 0; j < 8; ++j) {
        const float so = gv[32+j*4+0] + gv[32+j*4+1] + gv[32+j*4+2] + gv[32+j*4+3];
#pragma unroll
        for (int u = 0; u < 4; ++u) {
          const float eg = gv[j*4 + u];
          const float og = (so - gv[32 + j*4 + u]) * (1.f/3.f);
          sf += 0.25f * (W8[12 + j] * eg + W8[28 + j] * og);
        }
      }
      fin = sf;
    }
  }
  __syncthreads();
  f2 v = spl(0.f);
#pragma unroll
  for (int c = 0; c < 4; ++c) v = spl(W8[c]) * ch2[c] + v;
#pragma unroll
  for (int j = 0; j < 8; ++j) {
    v = spl(W8[4 + j]) * el2[j] + v;
    v = spl(W8[20 + j]) * ol2[j] + v;
  }
  float t = v.x + v.y;
  t += __shfl_xor(t, 1, 64);   // sum over all 4 users
  if (p == 0)
    out[b*2048 + n] = (fin + 0.25f * t) * 3.14159265358979f;
}

extern "C" void kernel_launch(void* const* d_in, const int* in_sizes, int n_in,
                              void* d_out, int out_size, void* d_ws, size_t ws_size,
                              hipStream_t stream) {
  const float* channel = (const float*)d_in[0];
  const float* We1 = (const float*)d_in[1];
  const float* be1 = (const float*)d_in[2];
  const float* We  = (const float*)d_in[3];
  const float* be  = (const float*)d_in[4];
  const float* Wo1 = (const float*)d_in[5];
  const float* bo1 = (const float*)d_in[6];
  const float* Wo  = (const float*)d_in[7];
  const float* bo  = (const float*)d_in[8];
  const float* W8  = (const float*)d_in[9];
  const float* b8  = (const float*)d_in[10];
  float* out  = (float*)d_out;
  float* part = (float*)d_ws;                       // 2*64*64 floats = 32768 B (cumulative)
  int*   gcnt = (int*)((char*)d_ws + 32768);        // 64 ints

  // stream-ordered zeroing of cumulative rows + counters (graph-capturable)
  hipMemsetAsync(d_ws, 0, 32768 + 64 * sizeof(int), stream);

  void* args[] = { (void*)&channel, (void*)&We1, (void*)&be1, (void*)&We, (void*)&be,
                   (void*)&Wo1, (void*)&bo1, (void*)&Wo, (void*)&bo,
                   (void*)&W8, (void*)&b8, (void*)&out, (void*)&part, (void*)&gcnt };
  hipLaunchCooperativeKernel((void*)risnet_kernel, dim3(GRID), dim3(TPB), args, 0, stream);
}